// Round 21
// baseline (119.594 us; speedup 1.0000x reference)
//
#include <hip/hip_runtime.h>
#include <hip/hip_bf16.h>
#include <math.h>

// Problem constants
#define BB 4
#define SS 128
#define CC 80          // C_MEL
#define HH 256         // D_MODEL
#define KK 9
#define PP 4           // (K-1)/2
#define TT 16          // MAX_DUR
#define NSEG 512       // B*S
#define G3 768         // 3*H
#define EPSV 1e-5f
#define XKP 96         // xg padded K (80 -> 96)

typedef short bf16x8 __attribute__((ext_vector_type(8)));
typedef float f32x4 __attribute__((ext_vector_type(4)));

#define HSTR 264       // h_lds row stride in bf16 elems (256 + 8 pad)

__device__ inline ushort f2bf(float f) {
  unsigned x = __float_as_uint(f);
  unsigned r = (x + 0x7FFF + ((x >> 16) & 1)) >> 16;  // RNE
  return (ushort)r;
}
__device__ inline float bf2f(ushort u) {
  return __uint_as_float(((unsigned)u) << 16);
}
__device__ inline float fsig(float x) { return 1.f / (1.f + __expf(-x)); }
__device__ inline float ftanh(float x) {
  float e = __expf(2.f * x);
  return 1.f - 2.f / (e + 1.f);
}

// ---------------- prep: starts, durations, perm + inverse perm ----------------
__global__ __launch_bounds__(512) void k_prep(const int* __restrict__ duration,
                                              const int* __restrict__ srclen,
                                              int* __restrict__ starts,
                                              int* __restrict__ dur,
                                              int* __restrict__ perm,
                                              int* __restrict__ iperm) {
  __shared__ int ds[512];
  __shared__ int hist[17];
  __shared__ int base[17];
  int tid = threadIdx.x;               // 0..511
  int b = tid >> 7, s = tid & 127;
  int v = (s < srclen[b]) ? duration[b * SS + s] : 0;
  ds[tid] = v;
  if (tid < 17) hist[tid] = 0;
  __syncthreads();
  int run = 0;
  for (int s2 = b * 128; s2 < tid; ++s2) run += ds[s2];
  starts[tid] = run;
  dur[tid] = v;
  atomicAdd(&hist[v], 1);
  __syncthreads();
  if (tid == 0) {
    int acc = 0;
    for (int q = 0; q < 17; q++) { base[q] = acc; acc += hist[q]; }
  }
  __syncthreads();
  int rank = atomicAdd(&base[v], 1);
  perm[rank] = tid;
  iperm[tid] = rank;
}

// ---------------- merged weight pack: whh + conv + w_ih ----------------------
__global__ __launch_bounds__(256) void k_packall(
    const float* __restrict__ whhf, const float* __restrict__ whhb,
    const float* __restrict__ w1, const float* __restrict__ g1v,
    const float* __restrict__ be1v, const float* __restrict__ w2,
    const float* __restrict__ wihf, const float* __restrict__ wihb,
    ushort* __restrict__ wp, ushort* __restrict__ wpc,
    ushort* __restrict__ wpx) {
  int idx = blockIdx.x * 256 + threadIdx.x;   // 0..552959
  if (idx < 393216) {
    int r = idx;
    int j = r & 7; r >>= 3;
    int lane = r & 63; r >>= 6;
    int ks = r & 7; r >>= 3;
    int tau = r % 6; r /= 6;
    int wv = r & 7; r >>= 3;
    int dir = r;
    int gate = tau >> 1, a = tau & 1;
    int n = gate * 256 + wv * 32 + a * 16 + (lane & 15);
    int k = ks * 32 + (lane >> 4) * 8 + j;
    float v = (dir ? whhb : whhf)[(size_t)n * HH + k];
    wp[idx] = f2bf(v);
  } else if (idx < 405504) {
    int tid = idx - 393216;
    if (tid < 8192) {
      int nt = tid >> 9;
      int lane = (tid >> 3) & 63;
      int j = tid & 7;
      int h = nt * 16 + (lane & 15);
      int k = (lane >> 4) * 8 + j;
      float val = 0.f;
      if (k < KK) val = w1[k * HH + h] * (g1v[h] * rsqrtf(1.f + EPSV));
      else if (k == KK) val = be1v[h];
      wpc[tid] = f2bf(val);
    } else {
      int q = tid - 8192;
      int ks = q >> 9;
      int lane = (q >> 3) & 63;
      int j = q & 7;
      int k = lane & 15;
      int h = ks * 32 + (lane >> 4) * 8 + j;
      float val = (k < KK) ? w2[k * HH + h] : 0.f;
      wpc[tid] = f2bf(val);
    }
  } else {
    int q = idx - 405504;                      // 0..147455
    int j = q & 7;
    int lane = (q >> 3) & 63;
    int qq = q >> 9;
    int ks = qq % 3;
    int nt = qq / 3;                           // 0..95
    int n = nt * 16 + (lane & 15);
    int k = ks * 32 + (lane >> 4) * 8 + j;
    float v = 0.f;
    if (k < CC) v = (n < G3) ? wihf[(size_t)n * CC + k]
                             : wihb[(size_t)(n - G3) * CC + k];
    wpx[q] = f2bf(v);
  }
}

// ---------------- conv stack + fused x-gate GEMM (G output bf16) -------------
// launch_bounds (512,2): 2 blocks/CU -> VGPR cap 128 -> a1r CAN be resident.
__global__ __launch_bounds__(512, 2) void k_conv(
    const float* __restrict__ mel, const int* __restrict__ starts,
    const int* __restrict__ dur, const int* __restrict__ iperm,
    const ushort* __restrict__ wpc, const ushort* __restrict__ wpx,
    const float* __restrict__ g2v, const float* __restrict__ be2v,
    const float* __restrict__ bihf, const float* __restrict__ bihb,
    ushort* __restrict__ xgb, ushort* __restrict__ G, int Mmel) {
  __shared__ __align__(16) ushort xs2[CC][32];   // 5 KB, rows zero-padded
  __shared__ __align__(16) ushort wlc2[4096];    // 8 KB: conv2 b2 frags
  __shared__ __align__(16) float zs[8][16][18];  // 9.2 KB per-wave Z staging
  __shared__ __align__(16) float xgs[16][81];    // 5.2 KB staged output

  const int seg = blockIdx.x;
  const int b = seg >> 7;
  const int d = dur[seg];
  const int st = starts[seg];
  const int tid = threadIdx.x;
  const int wv = tid >> 6;
  const int lane = tid & 63;
  const int u = lane & 15;           // t-column (= lrow)
  const int lgrp = lane >> 4;
  const int hi2 = lgrp >> 1;

  {
    const uint4* src = (const uint4*)(wpc + 8192);
    uint4* dst = (uint4*)wlc2;
    if (tid < 512) dst[tid] = src[tid];
  }
  for (int idx = tid; idx < CC * 16; idx += 512) {
    int c = idx >> 4, t = idx & 15;
    float v = (t < d) ? mel[(size_t)(b * Mmel + st + t) * CC + c] : 0.f;
    xs2[c][t + 4] = f2bf(v);
  }
  for (int idx = tid; idx < CC * 16; idx += 512) {
    int c = idx >> 4, q = idx & 15;
    int p = (q < 4) ? q : (q + 16);
    xs2[c][p] = 0;
  }

  bf16x8 a1r[16];
#pragma unroll
  for (int nt = 0; nt < 16; nt++) {
    a1r[nt] = *(const bf16x8*)&wpc[nt * 512 + lane * 8];
    asm volatile("" : "+v"(a1r[nt]));
  }

  const float g2 = g2v[0] * rsqrtf(1.f + EPSV);
  const float be2 = be2v[0];
  const bool urow = (u < d);
  const unsigned umask = urow ? 0xFFFFFFFFu : 0u;
  const int src0 = (((lane >> 4) & 1) << 5) + u;
  const int src1 = src0 + 16;
  __syncthreads();

#pragma unroll 1
  for (int ci = 0; ci < 10; ci++) {
    const int c = wv * 10 + ci;
    unsigned bw0 = 0, bw1 = 0, bw2 = 0, bw3 = 0;
    if (lgrp == 0) {
      ushort e0 = xs2[c][u + 0], e1 = xs2[c][u + 1];
      ushort e2 = xs2[c][u + 2], e3 = xs2[c][u + 3];
      ushort e4 = xs2[c][u + 4], e5 = xs2[c][u + 5];
      ushort e6 = xs2[c][u + 6], e7 = xs2[c][u + 7];
      bw0 = (unsigned)e0 | ((unsigned)e1 << 16);
      bw1 = (unsigned)e2 | ((unsigned)e3 << 16);
      bw2 = (unsigned)e4 | ((unsigned)e5 << 16);
      bw3 = (unsigned)e6 | ((unsigned)e7 << 16);
    } else if (lgrp == 1) {
      ushort e0 = xs2[c][u + 8];                  // k=8
      bw0 = (unsigned)e0 | (0x3F80u << 16);       // k=9: bias column = 1.0
    }
    int4 bi4 = make_int4(bw0, bw1, bw2, bw3);
    bf16x8 b1 = *(bf16x8*)&bi4;

    f32x4 accQ = {0.f, 0.f, 0.f, 0.f};

#pragma unroll
    for (int half = 0; half < 2; half++) {
      unsigned P0[8], P1[8];
#pragma unroll
      for (int i = 0; i < 8; i++) {
        f32x4 z = {0.f, 0.f, 0.f, 0.f};
        f32x4 y = __builtin_amdgcn_mfma_f32_16x16x32_bf16(a1r[half * 8 + i],
                                                          b1, z, 0, 0, 0);
        float y0 = fmaxf(y[0], 0.f), y1 = fmaxf(y[1], 0.f);
        float y2 = fmaxf(y[2], 0.f), y3 = fmaxf(y[3], 0.f);
        P0[i] = ((unsigned)__bfloat16_as_ushort(__float2bfloat16(y0)) |
                 ((unsigned)__bfloat16_as_ushort(__float2bfloat16(y1)) << 16)) & umask;
        P1[i] = ((unsigned)__bfloat16_as_ushort(__float2bfloat16(y2)) |
                 ((unsigned)__bfloat16_as_ushort(__float2bfloat16(y3)) << 16)) & umask;
      }
#pragma unroll
      for (int ks2 = 0; ks2 < 4; ks2++) {
        int ks = half * 4 + ks2;
        int v00 = __shfl((int)P0[2 * ks2], src0, 64);
        int v10 = __shfl((int)P0[2 * ks2 + 1], src0, 64);
        unsigned w0 = hi2 ? (unsigned)v10 : (unsigned)v00;   // (j0,j1)
        int v01 = __shfl((int)P1[2 * ks2], src0, 64);
        int v11 = __shfl((int)P1[2 * ks2 + 1], src0, 64);
        unsigned w1 = hi2 ? (unsigned)v11 : (unsigned)v01;   // (j2,j3)
        int v02 = __shfl((int)P0[2 * ks2], src1, 64);
        int v12 = __shfl((int)P0[2 * ks2 + 1], src1, 64);
        unsigned w2 = hi2 ? (unsigned)v12 : (unsigned)v02;   // (j4,j5)
        int v03 = __shfl((int)P1[2 * ks2], src1, 64);
        int v13 = __shfl((int)P1[2 * ks2 + 1], src1, 64);
        unsigned w3 = hi2 ? (unsigned)v13 : (unsigned)v03;   // (j6,j7)
        int4 ai4 = make_int4(w0, w1, w2, w3);
        bf16x8 a2 = *(bf16x8*)&ai4;
        bf16x8 b2 = *(const bf16x8*)&wlc2[ks * 512 + lane * 8];
        accQ = __builtin_amdgcn_mfma_f32_16x16x32_bf16(a2, b2, accQ, 0, 0, 0);
      }
    }

    if (u < KK) {
#pragma unroll
      for (int r = 0; r < 4; r++) zs[wv][lgrp * 4 + r][u] = accQ[r];
    }
    asm volatile("" ::: "memory");

    if (lgrp == 0) {
      float Q = 0.f;
#pragma unroll
      for (int k = 0; k < KK; k++) {
        int idx = u + k - PP;
        if (idx >= 0 && idx < 16) Q += zs[wv][idx][k];
      }
      float qf = urow ? fmaxf(Q * g2 + be2, 0.f) : 0.f;
      xgs[u][c] = qf;
    }
    asm volatile("" ::: "memory");
  }
  __syncthreads();

  // xgb store (bf16, K-padded to 96)
  for (int idx = tid; idx < 16 * XKP; idx += 512) {
    int t = idx / XKP, kk = idx - t * XKP;
    ushort v = (kk < CC) ? f2bf(xgs[t][kk]) : (ushort)0;
    xgb[(size_t)(seg * TT + t) * XKP + kk] = v;
  }
  __syncthreads();   // compiler drains vmcnt before barrier -> xgb visible

  // ---- fused x-gate GEMM: G rows prank*16 + t, bf16 output ----
  {
    const int prank = iperm[seg];
    const int dirp = wv >> 2;
    const int wloc = wv & 3;
    int ts = dirp ? (d - 1 - u) : u;
    ts = min(max(ts, 0), TT - 1);
    bf16x8 a[3];
#pragma unroll
    for (int ks = 0; ks < 3; ks++)
      a[ks] = *(const bf16x8*)&xgb[(size_t)(seg * TT + ts) * XKP + ks * 32 + lgrp * 8];
    const float* bsrc = dirp ? bihb : bihf;
#pragma unroll 1
    for (int ct = 0; ct < 12; ct++) {
      const int nt = dirp * 48 + wloc * 12 + ct;   // global ntile 0..95
      const int n0g = nt * 16;
      f32x4 cacc = {0.f, 0.f, 0.f, 0.f};
#pragma unroll
      for (int ks = 0; ks < 3; ks++) {
        bf16x8 bfrag = *(const bf16x8*)&wpx[(nt * 3 + ks) * 512 + lane * 8];
        cacc = __builtin_amdgcn_mfma_f32_16x16x32_bf16(a[ks], bfrag, cacc, 0, 0, 0);
      }
      float bias = bsrc[n0g + u - dirp * G3];
#pragma unroll
      for (int r = 0; r < 4; r++)
        G[(size_t)(prank * 16 + lgrp * 4 + r) * 1536 + n0g + u] =
            f2bf(cacc[r] + bias);
    }
  }
}

// ---------------- fused bidirectional GRU (bf16 G, prank-ordered, prefetch) --
// launch_bounds (512,1): 1 block/CU (LDS forces this anyway) -> VGPR cap 256
// -> wreg[4][8] (128 VGPR) can finally be register-resident; pinned.
__global__ __launch_bounds__(512, 1) void k_gru(
    const ushort* __restrict__ G, const ushort* __restrict__ wp,
    const float* __restrict__ bhhf, const float* __restrict__ bhhb,
    const int* __restrict__ dur, const int* __restrict__ perm,
    float* __restrict__ out) {
  __shared__ short h_lds[2][16 * HSTR];     // double-buffered bf16 h
  __shared__ ushort wlds[8 * 2 * 8 * 512];  // 131072 B: tau=4,5 frags per wave
  __shared__ int seg_s[16], d_s[16];

  const int tid = threadIdx.x;
  const int bi = blockIdx.x;           // 0..63
  const int dir = bi >> 5;
  const int grp = bi & 31;
  const int wv = tid >> 6;
  const int lane = tid & 63;
  const int lrow = lane & 15;
  const int lgrp = lane >> 4;

  if (tid < 16) {
    int seg = perm[grp * 16 + tid];
    seg_s[tid] = seg;
    d_s[tid] = dur[seg];
  }
  for (int idx = tid; idx < 2 * 16 * HSTR; idx += 512)
    ((short*)h_lds)[idx] = 0;

  const ushort* wb = wp + (size_t)(dir * 8 + wv) * 6 * 8 * 512 + lane * 8;
  bf16x8 wreg[4][8];
#pragma unroll
  for (int tau = 0; tau < 4; tau++)
#pragma unroll
    for (int ks = 0; ks < 8; ks++) {
      wreg[tau][ks] = *(const bf16x8*)&wb[(tau * 8 + ks) * 512];
      asm volatile("" : "+v"(wreg[tau][ks]));
    }
#pragma unroll
  for (int tt2 = 0; tt2 < 2; tt2++)
#pragma unroll
    for (int ks = 0; ks < 8; ks++) {
      bf16x8 v = *(const bf16x8*)&wb[((4 + tt2) * 8 + ks) * 512];
      *(bf16x8*)&wlds[((wv * 2 + tt2) * 8 + ks) * 512 + lane * 8] = v;
    }
  __syncthreads();

  int d4[4], seg4[4];
#pragma unroll
  for (int r = 0; r < 4; r++) {
    d4[r] = d_s[lgrp * 4 + r];
    seg4[r] = seg_s[lgrp * 4 + r];
  }
  int dmax = 0;
#pragma unroll
  for (int q = 0; q < 16; q++) dmax = max(dmax, d_s[q]);

  const int i0 = wv * 32 + lrow;
  const float* bh = dir ? bhhb : bhhf;
  float bias[3][2];
#pragma unroll
  for (int g = 0; g < 3; g++)
#pragma unroll
    for (int a = 0; a < 2; a++) bias[g][a] = bh[g * 256 + i0 + 16 * a];

  size_t gbase[4];
#pragma unroll
  for (int r = 0; r < 4; r++)
    gbase[r] = (size_t)((grp * 16 + lgrp * 4 + r) * 16) * 1536 + dir * G3
               + i0;

  float h[4][2] = {};
  float gxc[4][3][2];
  float gxn[4][3][2];

#pragma unroll
  for (int r = 0; r < 4; r++)
#pragma unroll
    for (int g = 0; g < 3; g++)
#pragma unroll
      for (int a = 0; a < 2; a++)
        gxc[r][g][a] = bf2f(G[gbase[r] + g * 256 + 16 * a]);

  for (int t = 0; t < dmax; t++) {
    const int cur = t & 1;
    const int tn = min(t + 1, TT - 1);
#pragma unroll
    for (int r = 0; r < 4; r++)
#pragma unroll
      for (int g = 0; g < 3; g++)
#pragma unroll
        for (int a = 0; a < 2; a++)
          gxn[r][g][a] = bf2f(G[gbase[r] + (size_t)tn * 1536 + g * 256 + 16 * a]);

    f32x4 acc[6];
#pragma unroll
    for (int tau = 0; tau < 6; tau++) acc[tau] = (f32x4){0.f, 0.f, 0.f, 0.f};
#pragma unroll
    for (int ks = 0; ks < 8; ks++) {
      bf16x8 av = *(const bf16x8*)&h_lds[cur][lrow * HSTR + ks * 32 + lgrp * 8];
#pragma unroll
      for (int tau = 0; tau < 4; tau++)
        acc[tau] = __builtin_amdgcn_mfma_f32_16x16x32_bf16(av, wreg[tau][ks],
                                                           acc[tau], 0, 0, 0);
#pragma unroll
      for (int tt2 = 0; tt2 < 2; tt2++) {
        bf16x8 wf = *(const bf16x8*)&wlds[((wv * 2 + tt2) * 8 + ks) * 512 + lane * 8];
        acc[4 + tt2] = __builtin_amdgcn_mfma_f32_16x16x32_bf16(av, wf,
                                                               acc[4 + tt2], 0, 0, 0);
      }
    }
#pragma unroll
    for (int r = 0; r < 4; r++) {
      if (t < d4[r]) {
#pragma unroll
        for (int a = 0; a < 2; a++) {
          float rr = fsig(gxc[r][0][a] + acc[a][r] + bias[0][a]);
          float zz = fsig(gxc[r][1][a] + acc[2 + a][r] + bias[1][a]);
          float nn = ftanh(gxc[r][2][a] + rr * (acc[4 + a][r] + bias[2][a]));
          h[r][a] = (1.f - zz) * nn + zz * h[r][a];
          h_lds[cur ^ 1][(lgrp * 4 + r) * HSTR + i0 + 16 * a] = (short)f2bf(h[r][a]);
        }
      }
    }
#pragma unroll
    for (int r = 0; r < 4; r++)
#pragma unroll
      for (int g = 0; g < 3; g++)
#pragma unroll
        for (int a = 0; a < 2; a++) gxc[r][g][a] = gxn[r][g][a];
    __syncthreads();
  }

#pragma unroll
  for (int r = 0; r < 4; r++)
#pragma unroll
    for (int a = 0; a < 2; a++)
      out[(size_t)seg4[r] * 512 + dir * 256 + i0 + 16 * a] = h[r][a];
}

extern "C" void kernel_launch(void* const* d_in, const int* in_sizes, int n_in,
                              void* d_out, int out_size, void* d_ws, size_t ws_size,
                              hipStream_t stream) {
  const float* mel = (const float*)d_in[0];
  const int Mmel = in_sizes[0] / (BB * CC);
  const int* duration = (const int*)d_in[2];
  const int* src_len = (const int*)d_in[3];
  const float* conv1_w = (const float*)d_in[5];
  const float* bn1_g = (const float*)d_in[6];
  const float* bn1_b = (const float*)d_in[7];
  const float* conv2_w = (const float*)d_in[8];
  const float* bn2_g = (const float*)d_in[9];
  const float* bn2_b = (const float*)d_in[10];
  const float* w_ih_f = (const float*)d_in[11];
  const float* w_hh_f = (const float*)d_in[12];
  const float* b_ih_f = (const float*)d_in[13];
  const float* b_hh_f = (const float*)d_in[14];
  const float* w_ih_b = (const float*)d_in[15];
  const float* w_hh_b = (const float*)d_in[16];
  const float* b_ih_b = (const float*)d_in[17];
  const float* b_hh_b = (const float*)d_in[18];

  char* w = (char*)d_ws;
  int* starts = (int*)w;            w += 512 * sizeof(int);
  int* dur = (int*)w;               w += 512 * sizeof(int);
  int* perm = (int*)w;              w += 512 * sizeof(int);
  int* iperm = (int*)w;             w += 512 * sizeof(int);
  ushort* xgb = (ushort*)w;         w += (size_t)NSEG * TT * XKP * sizeof(ushort);   // 1.57 MB
  ushort* G = (ushort*)w;           w += (size_t)NSEG * TT * 1536 * sizeof(ushort);  // 25.2 MB
  ushort* wp = (ushort*)w;          w += (size_t)2 * 8 * 6 * 8 * 512 * sizeof(ushort); // 786 KB
  ushort* wpc = (ushort*)w;         w += (size_t)12288 * sizeof(ushort);             // 24.6 KB
  ushort* wpx = (ushort*)w;         w += (size_t)96 * 3 * 512 * sizeof(ushort);      // 295 KB
  (void)ws_size; (void)n_in; (void)out_size;

  k_prep<<<1, 512, 0, stream>>>(duration, src_len, starts, dur, perm, iperm);
  k_packall<<<2160, 256, 0, stream>>>(w_hh_f, w_hh_b, conv1_w, bn1_g, bn1_b,
                                      conv2_w, w_ih_f, w_ih_b, wp, wpc, wpx);
  k_conv<<<NSEG, 512, 0, stream>>>(mel, starts, dur, iperm, wpc, wpx,
                                   bn2_g, bn2_b, b_ih_f, b_ih_b, xgb, G, Mmel);
  k_gru<<<64, 512, 0, stream>>>(G, wp, b_hh_f, b_hh_b, dur, perm, (float*)d_out);
}

// Round 22
// 113.082 us; speedup vs baseline: 1.0576x; 1.0576x over previous
//
#include <hip/hip_runtime.h>
#include <hip/hip_bf16.h>
#include <math.h>

// Problem constants
#define BB 4
#define SS 128
#define CC 80          // C_MEL
#define HH 256         // D_MODEL
#define KK 9
#define PP 4           // (K-1)/2
#define TT 16          // MAX_DUR
#define NSEG 512       // B*S
#define G3 768         // 3*H
#define EPSV 1e-5f
#define XKP 96         // xg padded K (80 -> 96)

typedef short bf16x8 __attribute__((ext_vector_type(8)));
typedef float f32x4 __attribute__((ext_vector_type(4)));

#define HSTR 264       // h_lds row stride in bf16 elems (256 + 8 pad)

__device__ inline ushort f2bf(float f) {
  unsigned x = __float_as_uint(f);
  unsigned r = (x + 0x7FFF + ((x >> 16) & 1)) >> 16;  // RNE
  return (ushort)r;
}
__device__ inline float bf2f(ushort u) {
  return __uint_as_float(((unsigned)u) << 16);
}
__device__ inline float fsig(float x) { return 1.f / (1.f + __expf(-x)); }
__device__ inline float ftanh(float x) {
  float e = __expf(2.f * x);
  return 1.f - 2.f / (e + 1.f);
}

// ---------------- prep: starts, durations, perm + inverse perm ----------------
__global__ __launch_bounds__(512) void k_prep(const int* __restrict__ duration,
                                              const int* __restrict__ srclen,
                                              int* __restrict__ starts,
                                              int* __restrict__ dur,
                                              int* __restrict__ perm,
                                              int* __restrict__ iperm) {
  __shared__ int ds[512];
  __shared__ int hist[17];
  __shared__ int base[17];
  int tid = threadIdx.x;               // 0..511
  int b = tid >> 7, s = tid & 127;
  int v = (s < srclen[b]) ? duration[b * SS + s] : 0;
  ds[tid] = v;
  if (tid < 17) hist[tid] = 0;
  __syncthreads();
  int run = 0;
  for (int s2 = b * 128; s2 < tid; ++s2) run += ds[s2];
  starts[tid] = run;
  dur[tid] = v;
  atomicAdd(&hist[v], 1);
  __syncthreads();
  if (tid == 0) {
    int acc = 0;
    for (int q = 0; q < 17; q++) { base[q] = acc; acc += hist[q]; }
  }
  __syncthreads();
  int rank = atomicAdd(&base[v], 1);
  perm[rank] = tid;
  iperm[tid] = rank;
}

// ---------------- merged weight pack: whh + conv + w_ih ----------------------
__global__ __launch_bounds__(256) void k_packall(
    const float* __restrict__ whhf, const float* __restrict__ whhb,
    const float* __restrict__ w1, const float* __restrict__ g1v,
    const float* __restrict__ be1v, const float* __restrict__ w2,
    const float* __restrict__ wihf, const float* __restrict__ wihb,
    ushort* __restrict__ wp, ushort* __restrict__ wpc,
    ushort* __restrict__ wpx) {
  int idx = blockIdx.x * 256 + threadIdx.x;   // 0..552959
  if (idx < 393216) {
    int r = idx;
    int j = r & 7; r >>= 3;
    int lane = r & 63; r >>= 6;
    int ks = r & 7; r >>= 3;
    int tau = r % 6; r /= 6;
    int wv = r & 7; r >>= 3;
    int dir = r;
    int gate = tau >> 1, a = tau & 1;
    int n = gate * 256 + wv * 32 + a * 16 + (lane & 15);
    int k = ks * 32 + (lane >> 4) * 8 + j;
    float v = (dir ? whhb : whhf)[(size_t)n * HH + k];
    wp[idx] = f2bf(v);
  } else if (idx < 405504) {
    int tid = idx - 393216;
    if (tid < 8192) {
      int nt = tid >> 9;
      int lane = (tid >> 3) & 63;
      int j = tid & 7;
      int h = nt * 16 + (lane & 15);
      int k = (lane >> 4) * 8 + j;
      float val = 0.f;
      if (k < KK) val = w1[k * HH + h] * (g1v[h] * rsqrtf(1.f + EPSV));
      else if (k == KK) val = be1v[h];
      wpc[tid] = f2bf(val);
    } else {
      int q = tid - 8192;
      int ks = q >> 9;
      int lane = (q >> 3) & 63;
      int j = q & 7;
      int k = lane & 15;
      int h = ks * 32 + (lane >> 4) * 8 + j;
      float val = (k < KK) ? w2[k * HH + h] : 0.f;
      wpc[tid] = f2bf(val);
    }
  } else {
    int q = idx - 405504;                      // 0..147455
    int j = q & 7;
    int lane = (q >> 3) & 63;
    int qq = q >> 9;
    int ks = qq % 3;
    int nt = qq / 3;                           // 0..95
    int n = nt * 16 + (lane & 15);
    int k = ks * 32 + (lane >> 4) * 8 + j;
    float v = 0.f;
    if (k < CC) v = (n < G3) ? wihf[(size_t)n * CC + k]
                             : wihb[(size_t)(n - G3) * CC + k];
    wpx[q] = f2bf(v);
  }
}

// ---------------- conv stack + fused x-gate GEMM (G output bf16) -------------
__global__ __launch_bounds__(512, 4) void k_conv(
    const float* __restrict__ mel, const int* __restrict__ starts,
    const int* __restrict__ dur, const int* __restrict__ iperm,
    const ushort* __restrict__ wpc, const ushort* __restrict__ wpx,
    const float* __restrict__ g2v, const float* __restrict__ be2v,
    const float* __restrict__ bihf, const float* __restrict__ bihb,
    ushort* __restrict__ xgb, ushort* __restrict__ G, int Mmel) {
  __shared__ __align__(16) ushort xs2[CC][32];   // 5 KB, rows zero-padded
  __shared__ __align__(16) ushort wlc2[4096];    // 8 KB: conv2 b2 frags
  __shared__ __align__(16) float zs[8][16][18];  // 9.2 KB per-wave Z staging
  __shared__ __align__(16) float xgs[16][81];    // 5.2 KB staged output

  const int seg = blockIdx.x;
  const int b = seg >> 7;
  const int d = dur[seg];
  const int st = starts[seg];
  const int tid = threadIdx.x;
  const int wv = tid >> 6;
  const int lane = tid & 63;
  const int u = lane & 15;           // t-column (= lrow)
  const int lgrp = lane >> 4;
  const int hi2 = lgrp >> 1;

  {
    const uint4* src = (const uint4*)(wpc + 8192);
    uint4* dst = (uint4*)wlc2;
    if (tid < 512) dst[tid] = src[tid];
  }
  for (int idx = tid; idx < CC * 16; idx += 512) {
    int c = idx >> 4, t = idx & 15;
    float v = (t < d) ? mel[(size_t)(b * Mmel + st + t) * CC + c] : 0.f;
    xs2[c][t + 4] = f2bf(v);
  }
  for (int idx = tid; idx < CC * 16; idx += 512) {
    int c = idx >> 4, q = idx & 15;
    int p = (q < 4) ? q : (q + 16);
    xs2[c][p] = 0;
  }

  bf16x8 a1r[16];
#pragma unroll
  for (int nt = 0; nt < 16; nt++) {
    a1r[nt] = *(const bf16x8*)&wpc[nt * 512 + lane * 8];
    asm volatile("" : "+v"(a1r[nt]));
  }

  const float g2 = g2v[0] * rsqrtf(1.f + EPSV);
  const float be2 = be2v[0];
  const bool urow = (u < d);
  const unsigned umask = urow ? 0xFFFFFFFFu : 0u;
  const int src0 = (((lane >> 4) & 1) << 5) + u;
  const int src1 = src0 + 16;
  __syncthreads();

#pragma unroll 1
  for (int ci = 0; ci < 10; ci++) {
    const int c = wv * 10 + ci;
    unsigned bw0 = 0, bw1 = 0, bw2 = 0, bw3 = 0;
    if (lgrp == 0) {
      ushort e0 = xs2[c][u + 0], e1 = xs2[c][u + 1];
      ushort e2 = xs2[c][u + 2], e3 = xs2[c][u + 3];
      ushort e4 = xs2[c][u + 4], e5 = xs2[c][u + 5];
      ushort e6 = xs2[c][u + 6], e7 = xs2[c][u + 7];
      bw0 = (unsigned)e0 | ((unsigned)e1 << 16);
      bw1 = (unsigned)e2 | ((unsigned)e3 << 16);
      bw2 = (unsigned)e4 | ((unsigned)e5 << 16);
      bw3 = (unsigned)e6 | ((unsigned)e7 << 16);
    } else if (lgrp == 1) {
      ushort e0 = xs2[c][u + 8];                  // k=8
      bw0 = (unsigned)e0 | (0x3F80u << 16);       // k=9: bias column = 1.0
    }
    int4 bi4 = make_int4(bw0, bw1, bw2, bw3);
    bf16x8 b1 = *(bf16x8*)&bi4;

    f32x4 accQ = {0.f, 0.f, 0.f, 0.f};

#pragma unroll
    for (int half = 0; half < 2; half++) {
      unsigned P0[8], P1[8];
#pragma unroll
      for (int i = 0; i < 8; i++) {
        f32x4 z = {0.f, 0.f, 0.f, 0.f};
        f32x4 y = __builtin_amdgcn_mfma_f32_16x16x32_bf16(a1r[half * 8 + i],
                                                          b1, z, 0, 0, 0);
        float y0 = fmaxf(y[0], 0.f), y1 = fmaxf(y[1], 0.f);
        float y2 = fmaxf(y[2], 0.f), y3 = fmaxf(y[3], 0.f);
        P0[i] = ((unsigned)__bfloat16_as_ushort(__float2bfloat16(y0)) |
                 ((unsigned)__bfloat16_as_ushort(__float2bfloat16(y1)) << 16)) & umask;
        P1[i] = ((unsigned)__bfloat16_as_ushort(__float2bfloat16(y2)) |
                 ((unsigned)__bfloat16_as_ushort(__float2bfloat16(y3)) << 16)) & umask;
      }
#pragma unroll
      for (int ks2 = 0; ks2 < 4; ks2++) {
        int ks = half * 4 + ks2;
        int v00 = __shfl((int)P0[2 * ks2], src0, 64);
        int v10 = __shfl((int)P0[2 * ks2 + 1], src0, 64);
        unsigned w0 = hi2 ? (unsigned)v10 : (unsigned)v00;   // (j0,j1)
        int v01 = __shfl((int)P1[2 * ks2], src0, 64);
        int v11 = __shfl((int)P1[2 * ks2 + 1], src0, 64);
        unsigned w1 = hi2 ? (unsigned)v11 : (unsigned)v01;   // (j2,j3)
        int v02 = __shfl((int)P0[2 * ks2], src1, 64);
        int v12 = __shfl((int)P0[2 * ks2 + 1], src1, 64);
        unsigned w2 = hi2 ? (unsigned)v12 : (unsigned)v02;   // (j4,j5)
        int v03 = __shfl((int)P1[2 * ks2], src1, 64);
        int v13 = __shfl((int)P1[2 * ks2 + 1], src1, 64);
        unsigned w3 = hi2 ? (unsigned)v13 : (unsigned)v03;   // (j6,j7)
        int4 ai4 = make_int4(w0, w1, w2, w3);
        bf16x8 a2 = *(bf16x8*)&ai4;
        bf16x8 b2 = *(const bf16x8*)&wlc2[ks * 512 + lane * 8];
        accQ = __builtin_amdgcn_mfma_f32_16x16x32_bf16(a2, b2, accQ, 0, 0, 0);
      }
    }

    if (u < KK) {
#pragma unroll
      for (int r = 0; r < 4; r++) zs[wv][lgrp * 4 + r][u] = accQ[r];
    }
    asm volatile("" ::: "memory");

    if (lgrp == 0) {
      float Q = 0.f;
#pragma unroll
      for (int k = 0; k < KK; k++) {
        int idx = u + k - PP;
        if (idx >= 0 && idx < 16) Q += zs[wv][idx][k];
      }
      float qf = urow ? fmaxf(Q * g2 + be2, 0.f) : 0.f;
      xgs[u][c] = qf;
    }
    asm volatile("" ::: "memory");
  }
  __syncthreads();

  // xgb store (bf16, K-padded to 96)
  for (int idx = tid; idx < 16 * XKP; idx += 512) {
    int t = idx / XKP, kk = idx - t * XKP;
    ushort v = (kk < CC) ? f2bf(xgs[t][kk]) : (ushort)0;
    xgb[(size_t)(seg * TT + t) * XKP + kk] = v;
  }
  __syncthreads();   // compiler drains vmcnt before barrier -> xgb visible

  // ---- fused x-gate GEMM: G rows prank*16 + t, bf16 output ----
  {
    const int prank = iperm[seg];
    const int dirp = wv >> 2;
    const int wloc = wv & 3;
    int ts = dirp ? (d - 1 - u) : u;
    ts = min(max(ts, 0), TT - 1);
    bf16x8 a[3];
#pragma unroll
    for (int ks = 0; ks < 3; ks++)
      a[ks] = *(const bf16x8*)&xgb[(size_t)(seg * TT + ts) * XKP + ks * 32 + lgrp * 8];
    const float* bsrc = dirp ? bihb : bihf;
#pragma unroll 1
    for (int ct = 0; ct < 12; ct++) {
      const int nt = dirp * 48 + wloc * 12 + ct;   // global ntile 0..95
      const int n0g = nt * 16;
      f32x4 cacc = {0.f, 0.f, 0.f, 0.f};
#pragma unroll
      for (int ks = 0; ks < 3; ks++) {
        bf16x8 bfrag = *(const bf16x8*)&wpx[(nt * 3 + ks) * 512 + lane * 8];
        cacc = __builtin_amdgcn_mfma_f32_16x16x32_bf16(a[ks], bfrag, cacc, 0, 0, 0);
      }
      float bias = bsrc[n0g + u - dirp * G3];
#pragma unroll
      for (int r = 0; r < 4; r++)
        G[(size_t)(prank * 16 + lgrp * 4 + r) * 1536 + n0g + u] =
            f2bf(cacc[r] + bias);
    }
  }
}

// ---------------- fused bidirectional GRU (bf16 G, prank-ordered, prefetch) --
__global__ __launch_bounds__(512, 2) void k_gru(
    const ushort* __restrict__ G, const ushort* __restrict__ wp,
    const float* __restrict__ bhhf, const float* __restrict__ bhhb,
    const int* __restrict__ dur, const int* __restrict__ perm,
    float* __restrict__ out) {
  __shared__ short h_lds[2][16 * HSTR];     // double-buffered bf16 h
  __shared__ ushort wlds[8 * 2 * 8 * 512];  // 131072 B: tau=4,5 frags per wave
  __shared__ int seg_s[16], d_s[16];

  const int tid = threadIdx.x;
  const int bi = blockIdx.x;           // 0..63
  const int dir = bi >> 5;
  const int grp = bi & 31;
  const int wv = tid >> 6;
  const int lane = tid & 63;
  const int lrow = lane & 15;
  const int lgrp = lane >> 4;

  if (tid < 16) {
    int seg = perm[grp * 16 + tid];
    seg_s[tid] = seg;
    d_s[tid] = dur[seg];
  }
  for (int idx = tid; idx < 2 * 16 * HSTR; idx += 512)
    ((short*)h_lds)[idx] = 0;

  const ushort* wb = wp + (size_t)(dir * 8 + wv) * 6 * 8 * 512 + lane * 8;
  bf16x8 wreg[4][8];
#pragma unroll
  for (int tau = 0; tau < 4; tau++)
#pragma unroll
    for (int ks = 0; ks < 8; ks++)
      wreg[tau][ks] = *(const bf16x8*)&wb[(tau * 8 + ks) * 512];
#pragma unroll
  for (int tt2 = 0; tt2 < 2; tt2++)
#pragma unroll
    for (int ks = 0; ks < 8; ks++) {
      bf16x8 v = *(const bf16x8*)&wb[((4 + tt2) * 8 + ks) * 512];
      *(bf16x8*)&wlds[((wv * 2 + tt2) * 8 + ks) * 512 + lane * 8] = v;
    }
  __syncthreads();

  int d4[4], seg4[4];
#pragma unroll
  for (int r = 0; r < 4; r++) {
    d4[r] = d_s[lgrp * 4 + r];
    seg4[r] = seg_s[lgrp * 4 + r];
  }
  int dmax = 0;
#pragma unroll
  for (int q = 0; q < 16; q++) dmax = max(dmax, d_s[q]);

  const int i0 = wv * 32 + lrow;
  const float* bh = dir ? bhhb : bhhf;
  float bias[3][2];
#pragma unroll
  for (int g = 0; g < 3; g++)
#pragma unroll
    for (int a = 0; a < 2; a++) bias[g][a] = bh[g * 256 + i0 + 16 * a];

  size_t gbase[4];
#pragma unroll
  for (int r = 0; r < 4; r++)
    gbase[r] = (size_t)((grp * 16 + lgrp * 4 + r) * 16) * 1536 + dir * G3
               + i0;

  float h[4][2] = {};
  float gxc[4][3][2];
  float gxn[4][3][2];

#pragma unroll
  for (int r = 0; r < 4; r++)
#pragma unroll
    for (int g = 0; g < 3; g++)
#pragma unroll
      for (int a = 0; a < 2; a++)
        gxc[r][g][a] = bf2f(G[gbase[r] + g * 256 + 16 * a]);

  for (int t = 0; t < dmax; t++) {
    const int cur = t & 1;
    const int tn = min(t + 1, TT - 1);
#pragma unroll
    for (int r = 0; r < 4; r++)
#pragma unroll
      for (int g = 0; g < 3; g++)
#pragma unroll
        for (int a = 0; a < 2; a++)
          gxn[r][g][a] = bf2f(G[gbase[r] + (size_t)tn * 1536 + g * 256 + 16 * a]);

    f32x4 acc[6];
#pragma unroll
    for (int tau = 0; tau < 6; tau++) acc[tau] = (f32x4){0.f, 0.f, 0.f, 0.f};
#pragma unroll
    for (int ks = 0; ks < 8; ks++) {
      bf16x8 av = *(const bf16x8*)&h_lds[cur][lrow * HSTR + ks * 32 + lgrp * 8];
#pragma unroll
      for (int tau = 0; tau < 4; tau++)
        acc[tau] = __builtin_amdgcn_mfma_f32_16x16x32_bf16(av, wreg[tau][ks],
                                                           acc[tau], 0, 0, 0);
#pragma unroll
      for (int tt2 = 0; tt2 < 2; tt2++) {
        bf16x8 wf = *(const bf16x8*)&wlds[((wv * 2 + tt2) * 8 + ks) * 512 + lane * 8];
        acc[4 + tt2] = __builtin_amdgcn_mfma_f32_16x16x32_bf16(av, wf,
                                                               acc[4 + tt2], 0, 0, 0);
      }
    }
#pragma unroll
    for (int r = 0; r < 4; r++) {
      if (t < d4[r]) {
#pragma unroll
        for (int a = 0; a < 2; a++) {
          float rr = fsig(gxc[r][0][a] + acc[a][r] + bias[0][a]);
          float zz = fsig(gxc[r][1][a] + acc[2 + a][r] + bias[1][a]);
          float nn = ftanh(gxc[r][2][a] + rr * (acc[4 + a][r] + bias[2][a]));
          h[r][a] = (1.f - zz) * nn + zz * h[r][a];
          h_lds[cur ^ 1][(lgrp * 4 + r) * HSTR + i0 + 16 * a] = (short)f2bf(h[r][a]);
        }
      }
    }
#pragma unroll
    for (int r = 0; r < 4; r++)
#pragma unroll
      for (int g = 0; g < 3; g++)
#pragma unroll
        for (int a = 0; a < 2; a++) gxc[r][g][a] = gxn[r][g][a];
    __syncthreads();
  }

#pragma unroll
  for (int r = 0; r < 4; r++)
#pragma unroll
    for (int a = 0; a < 2; a++)
      out[(size_t)seg4[r] * 512 + dir * 256 + i0 + 16 * a] = h[r][a];
}

extern "C" void kernel_launch(void* const* d_in, const int* in_sizes, int n_in,
                              void* d_out, int out_size, void* d_ws, size_t ws_size,
                              hipStream_t stream) {
  const float* mel = (const float*)d_in[0];
  const int Mmel = in_sizes[0] / (BB * CC);
  const int* duration = (const int*)d_in[2];
  const int* src_len = (const int*)d_in[3];
  const float* conv1_w = (const float*)d_in[5];
  const float* bn1_g = (const float*)d_in[6];
  const float* bn1_b = (const float*)d_in[7];
  const float* conv2_w = (const float*)d_in[8];
  const float* bn2_g = (const float*)d_in[9];
  const float* bn2_b = (const float*)d_in[10];
  const float* w_ih_f = (const float*)d_in[11];
  const float* w_hh_f = (const float*)d_in[12];
  const float* b_ih_f = (const float*)d_in[13];
  const float* b_hh_f = (const float*)d_in[14];
  const float* w_ih_b = (const float*)d_in[15];
  const float* w_hh_b = (const float*)d_in[16];
  const float* b_ih_b = (const float*)d_in[17];
  const float* b_hh_b = (const float*)d_in[18];

  char* w = (char*)d_ws;
  int* starts = (int*)w;            w += 512 * sizeof(int);
  int* dur = (int*)w;               w += 512 * sizeof(int);
  int* perm = (int*)w;              w += 512 * sizeof(int);
  int* iperm = (int*)w;             w += 512 * sizeof(int);
  ushort* xgb = (ushort*)w;         w += (size_t)NSEG * TT * XKP * sizeof(ushort);   // 1.57 MB
  ushort* G = (ushort*)w;           w += (size_t)NSEG * TT * 1536 * sizeof(ushort);  // 25.2 MB
  ushort* wp = (ushort*)w;          w += (size_t)2 * 8 * 6 * 8 * 512 * sizeof(ushort); // 786 KB
  ushort* wpc = (ushort*)w;         w += (size_t)12288 * sizeof(ushort);             // 24.6 KB
  ushort* wpx = (ushort*)w;         w += (size_t)96 * 3 * 512 * sizeof(ushort);      // 295 KB
  (void)ws_size; (void)n_in; (void)out_size;

  k_prep<<<1, 512, 0, stream>>>(duration, src_len, starts, dur, perm, iperm);
  k_packall<<<2160, 256, 0, stream>>>(w_hh_f, w_hh_b, conv1_w, bn1_g, bn1_b,
                                      conv2_w, w_ih_f, w_ih_b, wp, wpc, wpx);
  k_conv<<<NSEG, 512, 0, stream>>>(mel, starts, dur, iperm, wpc, wpx,
                                   bn2_g, bn2_b, b_ih_f, b_ih_b, xgb, G, Mmel);
  k_gru<<<64, 512, 0, stream>>>(G, wp, b_hh_f, b_hh_b, dur, perm, (float*)d_out);
}

// Round 23
// 110.276 us; speedup vs baseline: 1.0845x; 1.0254x over previous
//
#include <hip/hip_runtime.h>
#include <hip/hip_bf16.h>
#include <math.h>

// Problem constants
#define BB 4
#define SS 128
#define CC 80          // C_MEL
#define HH 256         // D_MODEL
#define KK 9
#define PP 4           // (K-1)/2
#define TT 16          // MAX_DUR
#define NSEG 512       // B*S
#define G3 768         // 3*H
#define EPSV 1e-5f
#define XKP 96         // xg padded K (80 -> 96)

typedef short bf16x8 __attribute__((ext_vector_type(8)));
typedef float f32x4 __attribute__((ext_vector_type(4)));

#define HSTR 264       // h_lds row stride in bf16 elems (256 + 8 pad)

__device__ inline ushort f2bf(float f) {
  unsigned x = __float_as_uint(f);
  unsigned r = (x + 0x7FFF + ((x >> 16) & 1)) >> 16;  // RNE
  return (ushort)r;
}
__device__ inline float bf2f(ushort u) {
  return __uint_as_float(((unsigned)u) << 16);
}
__device__ inline float fsig(float x) { return 1.f / (1.f + __expf(-x)); }
__device__ inline float ftanh(float x) {
  float e = __expf(2.f * x);
  return 1.f - 2.f / (e + 1.f);
}

// ------- merged prep + weight pack: blocks 0..1079 pack, block 1080 preps ----
__global__ __launch_bounds__(512) void k_packprep(
    const int* __restrict__ duration, const int* __restrict__ srclen,
    const float* __restrict__ whhf, const float* __restrict__ whhb,
    const float* __restrict__ w1, const float* __restrict__ g1v,
    const float* __restrict__ be1v, const float* __restrict__ w2,
    const float* __restrict__ wihf, const float* __restrict__ wihb,
    int* __restrict__ starts, int* __restrict__ dur,
    int* __restrict__ perm, int* __restrict__ iperm,
    ushort* __restrict__ wp, ushort* __restrict__ wpc,
    ushort* __restrict__ wpx) {
  if (blockIdx.x == 1080) {
    // ---- prep body (r22 k_prep, verbatim; blockIdx-uniform branch) ----
    __shared__ int ds[512];
    __shared__ int hist[17];
    __shared__ int base[17];
    int tid = threadIdx.x;               // 0..511
    int b = tid >> 7, s = tid & 127;
    int v = (s < srclen[b]) ? duration[b * SS + s] : 0;
    ds[tid] = v;
    if (tid < 17) hist[tid] = 0;
    __syncthreads();
    int run = 0;
    for (int s2 = b * 128; s2 < tid; ++s2) run += ds[s2];
    starts[tid] = run;
    dur[tid] = v;
    atomicAdd(&hist[v], 1);
    __syncthreads();
    if (tid == 0) {
      int acc = 0;
      for (int q = 0; q < 17; q++) { base[q] = acc; acc += hist[q]; }
    }
    __syncthreads();
    int rank = atomicAdd(&base[v], 1);
    perm[rank] = tid;
    iperm[tid] = rank;
    return;
  }

  int idx = blockIdx.x * 512 + threadIdx.x;   // 0..552959
  if (idx < 393216) {
    int r = idx;
    int j = r & 7; r >>= 3;
    int lane = r & 63; r >>= 6;
    int ks = r & 7; r >>= 3;
    int tau = r % 6; r /= 6;
    int wv = r & 7; r >>= 3;
    int dir = r;
    int gate = tau >> 1, a = tau & 1;
    int n = gate * 256 + wv * 32 + a * 16 + (lane & 15);
    int k = ks * 32 + (lane >> 4) * 8 + j;
    float v = (dir ? whhb : whhf)[(size_t)n * HH + k];
    wp[idx] = f2bf(v);
  } else if (idx < 405504) {
    int tid = idx - 393216;
    if (tid < 8192) {
      int nt = tid >> 9;
      int lane = (tid >> 3) & 63;
      int j = tid & 7;
      int h = nt * 16 + (lane & 15);
      int k = (lane >> 4) * 8 + j;
      float val = 0.f;
      if (k < KK) val = w1[k * HH + h] * (g1v[h] * rsqrtf(1.f + EPSV));
      else if (k == KK) val = be1v[h];
      wpc[tid] = f2bf(val);
    } else {
      int q = tid - 8192;
      int ks = q >> 9;
      int lane = (q >> 3) & 63;
      int j = q & 7;
      int k = lane & 15;
      int h = ks * 32 + (lane >> 4) * 8 + j;
      float val = (k < KK) ? w2[k * HH + h] : 0.f;
      wpc[tid] = f2bf(val);
    }
  } else {
    int q = idx - 405504;                      // 0..147455
    int j = q & 7;
    int lane = (q >> 3) & 63;
    int qq = q >> 9;
    int ks = qq % 3;
    int nt = qq / 3;                           // 0..95
    int n = nt * 16 + (lane & 15);
    int k = ks * 32 + (lane >> 4) * 8 + j;
    float v = 0.f;
    if (k < CC) v = (n < G3) ? wihf[(size_t)n * CC + k]
                             : wihb[(size_t)(n - G3) * CC + k];
    wpx[q] = f2bf(v);
  }
}

// ---------------- conv stack + fused x-gate GEMM (G output bf16) -------------
__global__ __launch_bounds__(512, 4) void k_conv(
    const float* __restrict__ mel, const int* __restrict__ starts,
    const int* __restrict__ dur, const int* __restrict__ iperm,
    const ushort* __restrict__ wpc, const ushort* __restrict__ wpx,
    const float* __restrict__ g2v, const float* __restrict__ be2v,
    const float* __restrict__ bihf, const float* __restrict__ bihb,
    ushort* __restrict__ xgb, ushort* __restrict__ G, int Mmel) {
  __shared__ __align__(16) ushort xs2[CC][32];   // 5 KB, rows zero-padded
  __shared__ __align__(16) ushort wlc2[4096];    // 8 KB: conv2 b2 frags
  __shared__ __align__(16) float zs[8][16][18];  // 9.2 KB per-wave Z staging
  __shared__ __align__(16) float xgs[16][81];    // 5.2 KB staged output

  const int seg = blockIdx.x;
  const int b = seg >> 7;
  const int d = dur[seg];
  const int st = starts[seg];
  const int tid = threadIdx.x;
  const int wv = tid >> 6;
  const int lane = tid & 63;
  const int u = lane & 15;           // t-column (= lrow)
  const int lgrp = lane >> 4;
  const int hi2 = lgrp >> 1;

  {
    const uint4* src = (const uint4*)(wpc + 8192);
    uint4* dst = (uint4*)wlc2;
    if (tid < 512) dst[tid] = src[tid];
  }
  for (int idx = tid; idx < CC * 16; idx += 512) {
    int c = idx >> 4, t = idx & 15;
    float v = (t < d) ? mel[(size_t)(b * Mmel + st + t) * CC + c] : 0.f;
    xs2[c][t + 4] = f2bf(v);
  }
  for (int idx = tid; idx < CC * 16; idx += 512) {
    int c = idx >> 4, q = idx & 15;
    int p = (q < 4) ? q : (q + 16);
    xs2[c][p] = 0;
  }

  bf16x8 a1r[16];
#pragma unroll
  for (int nt = 0; nt < 16; nt++) {
    a1r[nt] = *(const bf16x8*)&wpc[nt * 512 + lane * 8];
    asm volatile("" : "+v"(a1r[nt]));
  }

  const float g2 = g2v[0] * rsqrtf(1.f + EPSV);
  const float be2 = be2v[0];
  const bool urow = (u < d);
  const unsigned umask = urow ? 0xFFFFFFFFu : 0u;
  const int src0 = (((lane >> 4) & 1) << 5) + u;
  const int src1 = src0 + 16;
  __syncthreads();

#pragma unroll 1
  for (int ci = 0; ci < 10; ci++) {
    const int c = wv * 10 + ci;
    unsigned bw0 = 0, bw1 = 0, bw2 = 0, bw3 = 0;
    if (lgrp == 0) {
      ushort e0 = xs2[c][u + 0], e1 = xs2[c][u + 1];
      ushort e2 = xs2[c][u + 2], e3 = xs2[c][u + 3];
      ushort e4 = xs2[c][u + 4], e5 = xs2[c][u + 5];
      ushort e6 = xs2[c][u + 6], e7 = xs2[c][u + 7];
      bw0 = (unsigned)e0 | ((unsigned)e1 << 16);
      bw1 = (unsigned)e2 | ((unsigned)e3 << 16);
      bw2 = (unsigned)e4 | ((unsigned)e5 << 16);
      bw3 = (unsigned)e6 | ((unsigned)e7 << 16);
    } else if (lgrp == 1) {
      ushort e0 = xs2[c][u + 8];                  // k=8
      bw0 = (unsigned)e0 | (0x3F80u << 16);       // k=9: bias column = 1.0
    }
    int4 bi4 = make_int4(bw0, bw1, bw2, bw3);
    bf16x8 b1 = *(bf16x8*)&bi4;

    f32x4 accQ = {0.f, 0.f, 0.f, 0.f};

#pragma unroll
    for (int half = 0; half < 2; half++) {
      unsigned P0[8], P1[8];
#pragma unroll
      for (int i = 0; i < 8; i++) {
        f32x4 z = {0.f, 0.f, 0.f, 0.f};
        f32x4 y = __builtin_amdgcn_mfma_f32_16x16x32_bf16(a1r[half * 8 + i],
                                                          b1, z, 0, 0, 0);
        float y0 = fmaxf(y[0], 0.f), y1 = fmaxf(y[1], 0.f);
        float y2 = fmaxf(y[2], 0.f), y3 = fmaxf(y[3], 0.f);
        P0[i] = ((unsigned)__bfloat16_as_ushort(__float2bfloat16(y0)) |
                 ((unsigned)__bfloat16_as_ushort(__float2bfloat16(y1)) << 16)) & umask;
        P1[i] = ((unsigned)__bfloat16_as_ushort(__float2bfloat16(y2)) |
                 ((unsigned)__bfloat16_as_ushort(__float2bfloat16(y3)) << 16)) & umask;
      }
#pragma unroll
      for (int ks2 = 0; ks2 < 4; ks2++) {
        int ks = half * 4 + ks2;
        int v00 = __shfl((int)P0[2 * ks2], src0, 64);
        int v10 = __shfl((int)P0[2 * ks2 + 1], src0, 64);
        unsigned w0 = hi2 ? (unsigned)v10 : (unsigned)v00;   // (j0,j1)
        int v01 = __shfl((int)P1[2 * ks2], src0, 64);
        int v11 = __shfl((int)P1[2 * ks2 + 1], src0, 64);
        unsigned w1 = hi2 ? (unsigned)v11 : (unsigned)v01;   // (j2,j3)
        int v02 = __shfl((int)P0[2 * ks2], src1, 64);
        int v12 = __shfl((int)P0[2 * ks2 + 1], src1, 64);
        unsigned w2 = hi2 ? (unsigned)v12 : (unsigned)v02;   // (j4,j5)
        int v03 = __shfl((int)P1[2 * ks2], src1, 64);
        int v13 = __shfl((int)P1[2 * ks2 + 1], src1, 64);
        unsigned w3 = hi2 ? (unsigned)v13 : (unsigned)v03;   // (j6,j7)
        int4 ai4 = make_int4(w0, w1, w2, w3);
        bf16x8 a2 = *(bf16x8*)&ai4;
        bf16x8 b2 = *(const bf16x8*)&wlc2[ks * 512 + lane * 8];
        accQ = __builtin_amdgcn_mfma_f32_16x16x32_bf16(a2, b2, accQ, 0, 0, 0);
      }
    }

    if (u < KK) {
#pragma unroll
      for (int r = 0; r < 4; r++) zs[wv][lgrp * 4 + r][u] = accQ[r];
    }
    asm volatile("" ::: "memory");

    if (lgrp == 0) {
      float Q = 0.f;
#pragma unroll
      for (int k = 0; k < KK; k++) {
        int idx = u + k - PP;
        if (idx >= 0 && idx < 16) Q += zs[wv][idx][k];
      }
      float qf = urow ? fmaxf(Q * g2 + be2, 0.f) : 0.f;
      xgs[u][c] = qf;
    }
    asm volatile("" ::: "memory");
  }
  __syncthreads();

  // xgb store (bf16, K-padded to 96)
  for (int idx = tid; idx < 16 * XKP; idx += 512) {
    int t = idx / XKP, kk = idx - t * XKP;
    ushort v = (kk < CC) ? f2bf(xgs[t][kk]) : (ushort)0;
    xgb[(size_t)(seg * TT + t) * XKP + kk] = v;
  }
  __syncthreads();   // compiler drains vmcnt before barrier -> xgb visible

  // ---- fused x-gate GEMM: G rows prank*16 + t, bf16 output ----
  {
    const int prank = iperm[seg];
    const int dirp = wv >> 2;
    const int wloc = wv & 3;
    int ts = dirp ? (d - 1 - u) : u;
    ts = min(max(ts, 0), TT - 1);
    bf16x8 a[3];
#pragma unroll
    for (int ks = 0; ks < 3; ks++)
      a[ks] = *(const bf16x8*)&xgb[(size_t)(seg * TT + ts) * XKP + ks * 32 + lgrp * 8];
    const float* bsrc = dirp ? bihb : bihf;
#pragma unroll 1
    for (int ct = 0; ct < 12; ct++) {
      const int nt = dirp * 48 + wloc * 12 + ct;   // global ntile 0..95
      const int n0g = nt * 16;
      f32x4 cacc = {0.f, 0.f, 0.f, 0.f};
#pragma unroll
      for (int ks = 0; ks < 3; ks++) {
        bf16x8 bfrag = *(const bf16x8*)&wpx[(nt * 3 + ks) * 512 + lane * 8];
        cacc = __builtin_amdgcn_mfma_f32_16x16x32_bf16(a[ks], bfrag, cacc, 0, 0, 0);
      }
      float bias = bsrc[n0g + u - dirp * G3];
#pragma unroll
      for (int r = 0; r < 4; r++)
        G[(size_t)(prank * 16 + lgrp * 4 + r) * 1536 + n0g + u] =
            f2bf(cacc[r] + bias);
    }
  }
}

// ---------------- fused bidirectional GRU (bf16 G, prank-ordered, prefetch) --
__global__ __launch_bounds__(512, 2) void k_gru(
    const ushort* __restrict__ G, const ushort* __restrict__ wp,
    const float* __restrict__ bhhf, const float* __restrict__ bhhb,
    const int* __restrict__ dur, const int* __restrict__ perm,
    float* __restrict__ out) {
  __shared__ short h_lds[2][16 * HSTR];     // double-buffered bf16 h
  __shared__ ushort wlds[8 * 2 * 8 * 512];  // 131072 B: tau=4,5 frags per wave
  __shared__ int seg_s[16], d_s[16];

  const int tid = threadIdx.x;
  const int bi = blockIdx.x;           // 0..63
  const int dir = bi >> 5;
  const int grp = bi & 31;
  const int wv = tid >> 6;
  const int lane = tid & 63;
  const int lrow = lane & 15;
  const int lgrp = lane >> 4;

  if (tid < 16) {
    int seg = perm[grp * 16 + tid];
    seg_s[tid] = seg;
    d_s[tid] = dur[seg];
  }
  for (int idx = tid; idx < 2 * 16 * HSTR; idx += 512)
    ((short*)h_lds)[idx] = 0;

  const ushort* wb = wp + (size_t)(dir * 8 + wv) * 6 * 8 * 512 + lane * 8;
  bf16x8 wreg[4][8];
#pragma unroll
  for (int tau = 0; tau < 4; tau++)
#pragma unroll
    for (int ks = 0; ks < 8; ks++)
      wreg[tau][ks] = *(const bf16x8*)&wb[(tau * 8 + ks) * 512];
#pragma unroll
  for (int tt2 = 0; tt2 < 2; tt2++)
#pragma unroll
    for (int ks = 0; ks < 8; ks++) {
      bf16x8 v = *(const bf16x8*)&wb[((4 + tt2) * 8 + ks) * 512];
      *(bf16x8*)&wlds[((wv * 2 + tt2) * 8 + ks) * 512 + lane * 8] = v;
    }
  __syncthreads();

  int d4[4], seg4[4];
#pragma unroll
  for (int r = 0; r < 4; r++) {
    d4[r] = d_s[lgrp * 4 + r];
    seg4[r] = seg_s[lgrp * 4 + r];
  }
  int dmax = 0;
#pragma unroll
  for (int q = 0; q < 16; q++) dmax = max(dmax, d_s[q]);

  const int i0 = wv * 32 + lrow;
  const float* bh = dir ? bhhb : bhhf;
  float bias[3][2];
#pragma unroll
  for (int g = 0; g < 3; g++)
#pragma unroll
    for (int a = 0; a < 2; a++) bias[g][a] = bh[g * 256 + i0 + 16 * a];

  size_t gbase[4];
#pragma unroll
  for (int r = 0; r < 4; r++)
    gbase[r] = (size_t)((grp * 16 + lgrp * 4 + r) * 16) * 1536 + dir * G3
               + i0;

  float h[4][2] = {};
  float gxc[4][3][2];
  float gxn[4][3][2];

#pragma unroll
  for (int r = 0; r < 4; r++)
#pragma unroll
    for (int g = 0; g < 3; g++)
#pragma unroll
      for (int a = 0; a < 2; a++)
        gxc[r][g][a] = bf2f(G[gbase[r] + g * 256 + 16 * a]);

  for (int t = 0; t < dmax; t++) {
    const int cur = t & 1;
    const int tn = min(t + 1, TT - 1);
#pragma unroll
    for (int r = 0; r < 4; r++)
#pragma unroll
      for (int g = 0; g < 3; g++)
#pragma unroll
        for (int a = 0; a < 2; a++)
          gxn[r][g][a] = bf2f(G[gbase[r] + (size_t)tn * 1536 + g * 256 + 16 * a]);

    f32x4 acc[6];
#pragma unroll
    for (int tau = 0; tau < 6; tau++) acc[tau] = (f32x4){0.f, 0.f, 0.f, 0.f};
#pragma unroll
    for (int ks = 0; ks < 8; ks++) {
      bf16x8 av = *(const bf16x8*)&h_lds[cur][lrow * HSTR + ks * 32 + lgrp * 8];
#pragma unroll
      for (int tau = 0; tau < 4; tau++)
        acc[tau] = __builtin_amdgcn_mfma_f32_16x16x32_bf16(av, wreg[tau][ks],
                                                           acc[tau], 0, 0, 0);
#pragma unroll
      for (int tt2 = 0; tt2 < 2; tt2++) {
        bf16x8 wf = *(const bf16x8*)&wlds[((wv * 2 + tt2) * 8 + ks) * 512 + lane * 8];
        acc[4 + tt2] = __builtin_amdgcn_mfma_f32_16x16x32_bf16(av, wf,
                                                               acc[4 + tt2], 0, 0, 0);
      }
    }
#pragma unroll
    for (int r = 0; r < 4; r++) {
      if (t < d4[r]) {
#pragma unroll
        for (int a = 0; a < 2; a++) {
          float rr = fsig(gxc[r][0][a] + acc[a][r] + bias[0][a]);
          float zz = fsig(gxc[r][1][a] + acc[2 + a][r] + bias[1][a]);
          float nn = ftanh(gxc[r][2][a] + rr * (acc[4 + a][r] + bias[2][a]));
          h[r][a] = (1.f - zz) * nn + zz * h[r][a];
          h_lds[cur ^ 1][(lgrp * 4 + r) * HSTR + i0 + 16 * a] = (short)f2bf(h[r][a]);
        }
      }
    }
#pragma unroll
    for (int r = 0; r < 4; r++)
#pragma unroll
      for (int g = 0; g < 3; g++)
#pragma unroll
        for (int a = 0; a < 2; a++) gxc[r][g][a] = gxn[r][g][a];
    __syncthreads();
  }

#pragma unroll
  for (int r = 0; r < 4; r++)
#pragma unroll
    for (int a = 0; a < 2; a++)
      out[(size_t)seg4[r] * 512 + dir * 256 + i0 + 16 * a] = h[r][a];
}

extern "C" void kernel_launch(void* const* d_in, const int* in_sizes, int n_in,
                              void* d_out, int out_size, void* d_ws, size_t ws_size,
                              hipStream_t stream) {
  const float* mel = (const float*)d_in[0];
  const int Mmel = in_sizes[0] / (BB * CC);
  const int* duration = (const int*)d_in[2];
  const int* src_len = (const int*)d_in[3];
  const float* conv1_w = (const float*)d_in[5];
  const float* bn1_g = (const float*)d_in[6];
  const float* bn1_b = (const float*)d_in[7];
  const float* conv2_w = (const float*)d_in[8];
  const float* bn2_g = (const float*)d_in[9];
  const float* bn2_b = (const float*)d_in[10];
  const float* w_ih_f = (const float*)d_in[11];
  const float* w_hh_f = (const float*)d_in[12];
  const float* b_ih_f = (const float*)d_in[13];
  const float* b_hh_f = (const float*)d_in[14];
  const float* w_ih_b = (const float*)d_in[15];
  const float* w_hh_b = (const float*)d_in[16];
  const float* b_ih_b = (const float*)d_in[17];
  const float* b_hh_b = (const float*)d_in[18];

  char* w = (char*)d_ws;
  int* starts = (int*)w;            w += 512 * sizeof(int);
  int* dur = (int*)w;               w += 512 * sizeof(int);
  int* perm = (int*)w;              w += 512 * sizeof(int);
  int* iperm = (int*)w;             w += 512 * sizeof(int);
  ushort* xgb = (ushort*)w;         w += (size_t)NSEG * TT * XKP * sizeof(ushort);   // 1.57 MB
  ushort* G = (ushort*)w;           w += (size_t)NSEG * TT * 1536 * sizeof(ushort);  // 25.2 MB
  ushort* wp = (ushort*)w;          w += (size_t)2 * 8 * 6 * 8 * 512 * sizeof(ushort); // 786 KB
  ushort* wpc = (ushort*)w;         w += (size_t)12288 * sizeof(ushort);             // 24.6 KB
  ushort* wpx = (ushort*)w;         w += (size_t)96 * 3 * 512 * sizeof(ushort);      // 295 KB
  (void)ws_size; (void)n_in; (void)out_size;

  k_packprep<<<1081, 512, 0, stream>>>(duration, src_len,
                                       w_hh_f, w_hh_b, conv1_w, bn1_g, bn1_b,
                                       conv2_w, w_ih_f, w_ih_b,
                                       starts, dur, perm, iperm, wp, wpc, wpx);
  k_conv<<<NSEG, 512, 0, stream>>>(mel, starts, dur, iperm, wpc, wpx,
                                   bn2_g, bn2_b, b_ih_f, b_ih_b, xgb, G, Mmel);
  k_gru<<<64, 512, 0, stream>>>(G, wp, b_hh_f, b_hh_b, dur, perm, (float*)d_out);
}